// Round 1
// 593.309 us; speedup vs baseline: 1.0746x; 1.0746x over previous
//
#include <hip/hip_runtime.h>

#define T_STEPS 1000
#define NB 256
#define DZ 64
#define DH 256
#define DS 16
#define CHUNK 64
#define NCHUNK 16   // 16*64 = 1024 >= 1000; trailing 24 steps computed, unstored

// LDS-only barrier: drains lgkmcnt (LDS ordering) but NOT vmcnt.
// Safe: global loads land in private regs; global stores are never read back.
__device__ __forceinline__ void barrier_lgkm() {
    asm volatile("s_waitcnt lgkmcnt(0)\n\ts_barrier" ::: "memory");
}

// VALU-pipe cross-lane add via DPP (fuses to v_add_f32_dpp).
// CTRL: 0xB1 = quad_perm[1,0,3,2] (xor1); 0x4E = quad_perm[2,3,0,1] (xor2);
//       0x121/0x122/0x124/0x128 = row_ror 1/2/4/8.
template<int CTRL>
__device__ __forceinline__ float dpp_add(float x) {
    int y = __builtin_amdgcn_update_dpp(0, __float_as_int(x), CTRL, 0xF, 0xF, true);
    return x + __int_as_float(y);
}
// Sum across the 16 lanes of a DPP row (every lane ends with the row total).
__device__ __forceinline__ float row16_allsum(float x) {
    x = dpp_add<0x128>(x);   // += ror8
    x = dpp_add<0x124>(x);   // += ror4
    x = dpp_add<0x122>(x);   // += ror2
    x = dpp_add<0x121>(x);   // += ror1
    return x;
}

// One block per trial b; 1024 threads = 16 waves = 4 waves/SIMD.
// Round-7 change: double resident waves (2->4 per SIMD) to hide the per-step
// LDS round-trip + barrier latency that capped the 512-thread version at
// VALUBusy ~52%. Per-thread work halves:
//   Phase 1: 4-lane QUAD owns h=tid>>2; member q covers z[16q..16q+16)
//            (4 b128 broadcast reads + 16 FMA), quad butterfly via two
//            quad_perm DPP adds; q==0 writes za_sh (skewed).
//   Phase 2: 16-lane row R=tid>>4 owns ONE j; lane r4 covers h in
//            [16*r4,16*r4+16) from skewed za_sh (2-way = free) + C[j][r4]*s_t[r4];
//            row_ror DPP rotation-reduce gives every lane the full sum.
// 2 LDS-only barriers/step. Out-address is pointer-incremented (no 64-bit
// multiply per step).
__global__ __launch_bounds__(1024)
__attribute__((amdgpu_waves_per_eu(4, 4)))
void plrnn_scan(const float* __restrict__ z0, const float* __restrict__ s,
                const float* __restrict__ A,  const float* __restrict__ W1,
                const float* __restrict__ W2, const float* __restrict__ h1,
                const float* __restrict__ h2, const float* __restrict__ C,
                float* __restrict__ out)
{
    const int tid = threadIdx.x;
    const int b   = blockIdx.x;
    const int h   = tid >> 2;            // phase-1 hidden unit (quad-owned)
    const int q   = tid & 3;             // which 16-wide quarter of the W1 dot
    const int j   = tid >> 4;            // phase-2 z output (row-owned), 0..63
    const int r4  = tid & 15;            // lane within row = 16-h slice

    __shared__ __align__(16) float z_sh[DZ];
    __shared__ __align__(16) float za_sh[320];        // skew: idx = h + (h>>4)*4
    __shared__ __align__(16) float s_sh[CHUNK * DS];  // 64 steps of s[t][b][0..15]

    // ---- loop-invariant weights (32 floats + C scalar) ----
    float4 w1v[4];    // W1[b][h][16q .. +16)  == 16 consecutive floats at 16*tid
    {
        const float4* p = (const float4*)(W1 + (size_t)b * DH * DZ) + 4 * tid;
        #pragma unroll
        for (int k = 0; k < 4; ++k) w1v[k] = p[k];
    }
    float4 w2v[4];    // W2[b][j][16*r4 .. +16) == 16 consecutive floats at 16*tid
    {
        const float4* p = (const float4*)(W2 + (size_t)b * DZ * DH) + 4 * tid;
        #pragma unroll
        for (int k = 0; k < 4; ++k) w2v[k] = p[k];
    }
    const float cj  = C[tid];             // C[j][r4]: DZ*DS == 1024 == blockDim
    const float h1r = h1[h];
    const float Aj  = A[j];
    const float h2j = h2[j];
    float zr = z0[b * DZ + j];            // z state for the row's j (replicated x16)

    if (tid < DZ) z_sh[tid] = z0[b * DZ + tid];

    // s prefetch: thread tid holds s[t0+srow][b][scol] for the NEXT chunk
    const int srow = tid >> 4, scol = tid & 15;
    float sreg = s[(size_t)min(srow, T_STEPS - 1) * NB * DS + (size_t)b * DS + scol];

    const int zi = h + ((h >> 4) << 2);   // skewed za_sh index for phase-1 store
    float* outp = out + (size_t)b * DZ + j;   // advanced by NB*DZ per step

    __syncthreads();

    for (int ci = 0; ci < NCHUNK; ++ci) {
        const int t0 = ci * CHUNK;
        s_sh[tid] = sreg;                 // visible after this step's barrier A
        {
            int tl = min(t0 + CHUNK + srow, T_STEPS - 1);
            sreg = s[(size_t)tl * NB * DS + (size_t)b * DS + scol];
        }

        #pragma unroll 4
        for (int tt = 0; tt < CHUNK; ++tt) {
            // ---- phase 1: Wz[h] = W1 row · z (LDS broadcast reads, free) ----
            const float4* z4 = (const float4*)(z_sh + 16 * q);
            float a0 = 0.f, a1 = 0.f, a2 = 0.f, a3 = 0.f;
            #pragma unroll
            for (int k = 0; k < 4; ++k) {
                float4 zv = z4[k];
                a0 = fmaf(w1v[k].x, zv.x, a0);
                a1 = fmaf(w1v[k].y, zv.y, a1);
                a2 = fmaf(w1v[k].z, zv.z, a2);
                a3 = fmaf(w1v[k].w, zv.w, a3);
            }
            float p1 = (a0 + a1) + (a2 + a3);
            p1 = dpp_add<0xB1>(p1);       // quad butterfly: += lane^1
            p1 = dpp_add<0x4E>(p1);       //                 += lane^2
            float za = fmaxf(p1 + h1r, 0.f) - fmaxf(p1, 0.f);
            if (q == 0) za_sh[zi] = za;
            barrier_lgkm();               // A: za_sh (+ s_sh at chunk start) visible

            // ---- phase 2: row computes z_new[j] over full h ----
            const float4* q4 = (const float4*)(za_sh + 20 * r4);  // skewed 16-slice
            float sv = s_sh[tt * DS + r4];                        // this lane's s elem
            float p00 = cj * sv, p01 = 0.f, p02 = 0.f, p03 = 0.f; // fold C·s in
            #pragma unroll
            for (int k = 0; k < 4; ++k) {
                float4 v = q4[k];
                p00 = fmaf(w2v[k].x, v.x, p00);
                p01 = fmaf(w2v[k].y, v.y, p01);
                p02 = fmaf(w2v[k].z, v.z, p02);
                p03 = fmaf(w2v[k].w, v.w, p03);
            }
            float pa = (p00 + p01) + (p02 + p03);
            pa = row16_allsum(pa);        // VALU DPP rotation reduce (no LDS)

            // ---- epilogue: every lane of the row holds the full sum ----
            float zn = fmaf(Aj, zr, pa + h2j);
            zr = zn;
            const int t = t0 + tt;
            if (r4 == 0) {
                z_sh[j] = zn;
                if (t < T_STEPS) *outp = zn;
            }
            outp += NB * DZ;
            barrier_lgkm();               // B: z_sh update visible for next phase 1
        }
    }
}

extern "C" void kernel_launch(void* const* d_in, const int* in_sizes, int n_in,
                              void* d_out, int out_size, void* d_ws, size_t ws_size,
                              hipStream_t stream) {
    const float* z0p = (const float*)d_in[0];
    const float* sp  = (const float*)d_in[1];
    const float* Ap  = (const float*)d_in[2];
    const float* W1p = (const float*)d_in[3];
    const float* W2p = (const float*)d_in[4];
    const float* h1p = (const float*)d_in[5];
    const float* h2p = (const float*)d_in[6];
    const float* Cp  = (const float*)d_in[7];

    plrnn_scan<<<dim3(NB), dim3(1024), 0, stream>>>(z0p, sp, Ap, W1p, W2p, h1p, h2p, Cp,
                                                    (float*)d_out);
}